// Round 9
// baseline (251.318 us; speedup 1.0000x reference)
//
#include <hip/hip_runtime.h>

typedef _Float16 f16;
typedef __attribute__((ext_vector_type(4))) _Float16 f16x4;
typedef __attribute__((ext_vector_type(8))) _Float16 f16x8;
typedef __attribute__((ext_vector_type(4))) float f32x4;

#define B_ 4
#define N_ 2048
#define D_ 1024

#define FENCE asm volatile("" ::: "memory")

// ---------------------------------------------------------------- cast fp32->fp16 + rowsum zeroing
__global__ __launch_bounds__(256) void k_cast_all(const float4* __restrict__ x,
                                                  const float4* __restrict__ wq,
                                                  const float4* __restrict__ wk,
                                                  const float4* __restrict__ wv,
                                                  f16x4* __restrict__ xo,
                                                  f16x4* __restrict__ wqo,
                                                  f16x4* __restrict__ wko,
                                                  f16x4* __restrict__ wvo,
                                                  float* __restrict__ rowsum) {
  int b = blockIdx.x;
  if (b >= 11264) {                      // 32 blocks zero the 8192-float rowsum
    rowsum[(b - 11264) * 256 + threadIdx.x] = 0.f;
    return;
  }
  const float4* in;
  f16x4* out;
  int idx;
  if (b < 8192)       { in = x;  out = xo;  idx = b * 256 + threadIdx.x; }
  else if (b < 9216)  { in = wq; out = wqo; idx = (b - 8192) * 256 + threadIdx.x; }
  else if (b < 10240) { in = wk; out = wko; idx = (b - 9216) * 256 + threadIdx.x; }
  else                { in = wv; out = wvo; idx = (b - 10240) * 256 + threadIdx.x; }
  float4 v = in[idx];
  f16x4 o = { (_Float16)v.x, (_Float16)v.y, (_Float16)v.z, (_Float16)v.w };
  out[idx] = o;
}

// ---------------------------------------------------------------- staging (proven-clean geometry)
// Half-tile = 128 rows x 128 B (BK=64 f16). 16B chunks XOR-swizzled by (row&7) on the
// GLOBAL source (LDS dest linear per global_load_lds constraint); reads apply the same
// XOR -> both-sides involution.
// 512-thread version: 2 loads/thread (for frozen gemm_d128).
__device__ __forceinline__ void stage_half(const char* g0, int ldB, int kByte,
                                           char* slot, int tid) {
#pragma unroll
  for (int r = 0; r < 2; ++r) {
    int lin = r * 8192 + tid * 16;
    int row = lin >> 7;
    int lch = ((lin >> 4) & 7) ^ (row & 7);
    const char* g = g0 + (long)row * ldB + kByte + lch * 16;
    char* l = slot + r * 8192 + ((tid >> 6) << 10);   // wave-uniform base; HW adds lane*16
    __builtin_amdgcn_global_load_lds(
        (const __attribute__((address_space(1))) unsigned int*)g,
        (__attribute__((address_space(3))) unsigned int*)l, 16, 0, 0);
  }
}
// 256-thread version: 4 loads/thread (for gemm4w).
__device__ __forceinline__ void stage_half4(const char* g0, int ldB, int kByte,
                                            char* slot, int tid) {
#pragma unroll
  for (int r = 0; r < 4; ++r) {
    int lin = r * 4096 + tid * 16;
    int row = lin >> 7;
    int lch = ((lin >> 4) & 7) ^ (row & 7);
    const char* g = g0 + (long)row * ldB + kByte + lch * 16;
    char* l = slot + r * 4096 + ((tid >> 6) << 10);   // wave-uniform base; HW adds lane*16
    __builtin_amdgcn_global_load_lds(
        (const __attribute__((address_space(1))) unsigned int*)g,
        (__attribute__((address_space(3))) unsigned int*)l, 16, 0, 0);
  }
}

// ---------------------------------------------------------------- 512-thr fragment/MFMA macros (d128)
#define RD_A(dst, base)                                                          \
  _Pragma("unroll") for (int i_ = 0; i_ < 4; ++i_) {                             \
    int rA_ = wm * 64 + i_ * 16 + l16;                                           \
    _Pragma("unroll") for (int k_ = 0; k_ < 2; ++k_)                             \
      dst[i_][k_] = *(const f16x8*)((base) + rA_ * 128 +                         \
                                    ((((k_ << 2) | quad) ^ l7) << 4));           \
  }
#define RD_B(dst, base)                                                          \
  _Pragma("unroll") for (int j_ = 0; j_ < 2; ++j_) {                             \
    int rB_ = wn * 32 + j_ * 16 + l16;                                           \
    _Pragma("unroll") for (int k_ = 0; k_ < 2; ++k_)                             \
      dst[j_][k_] = *(const f16x8*)((base) + rB_ * 128 +                         \
                                    ((((k_ << 2) | quad) ^ l7) << 4));           \
  }
#define MFMA8(Av, Bv, BH)                                                        \
  __builtin_amdgcn_s_setprio(1);                                                 \
  _Pragma("unroll") for (int i_ = 0; i_ < 4; ++i_)                               \
  _Pragma("unroll") for (int j_ = 0; j_ < 2; ++j_)                               \
  _Pragma("unroll") for (int k_ = 0; k_ < 2; ++k_)                               \
    acc[i_][BH][j_] = __builtin_amdgcn_mfma_f32_16x16x32_f16(                    \
        Av[i_][k_], Bv[j_][k_], acc[i_][BH][j_], 0, 0, 0);                       \
  __builtin_amdgcn_s_setprio(0);

// ---------------------------------------------------------------- 4-wave fragment/MFMA macros
#define RD_A8W(dst, base)                                                        \
  _Pragma("unroll") for (int i_ = 0; i_ < 8; ++i_)                               \
  _Pragma("unroll") for (int k_ = 0; k_ < 2; ++k_)                               \
    dst[i_][k_] = *(const f16x8*)((base) + (i_ * 16 + l16) * 128 +               \
                                  ((((k_ << 2) | quad) ^ l7) << 4));
#define RD_B2W(dst, base, jp)                                                    \
  _Pragma("unroll") for (int jj_ = 0; jj_ < 2; ++jj_)                            \
  _Pragma("unroll") for (int k_ = 0; k_ < 2; ++k_)                               \
    dst[(jp) * 2 + jj_][k_] = *(const f16x8*)((base) +                           \
        (((jp) * 2 + jj_) * 16 + l16) * 128 + ((((k_ << 2) | quad) ^ l7) << 4));
#define MFMA_P4(Av, Bv, Cc, jp)                                                  \
  __builtin_amdgcn_s_setprio(1);                                                 \
  _Pragma("unroll") for (int i_ = 0; i_ < 8; ++i_)                               \
  _Pragma("unroll") for (int jj_ = 0; jj_ < 2; ++jj_)                            \
  _Pragma("unroll") for (int k_ = 0; k_ < 2; ++k_)                               \
    Cc[i_][(jp) * 2 + jj_] = __builtin_amdgcn_mfma_f32_16x16x32_f16(             \
        Av[i_][k_], Bv[(jp) * 2 + jj_][k_], Cc[i_][(jp) * 2 + jj_], 0, 0, 0);    \
  __builtin_amdgcn_s_setprio(0);

// ---------------------------------------------------------------- 256x256 4-WAVE NT GEMM
// 4 waves (2M x 2N), wave tile 128x128 (square -> minimal LDS bytes/FLOP:
// 131 KB reads + 64 KB DMA writes = ~2054 cy vs MFMA 2066 cy per K-tile/CU;
// the 8-wave 128x64 layout was 2825 cy -> its 42% alternation ceiling).
// acc 256 VGPR + frags 128 -> ~420 regs, 1 wave/SIMD (launch_bounds(256,1)).
// Per tile: vmcnt(0) [t's halves landed; staged a FULL TILE ago => ~free];
// barrier; stage t+1 (16 loads, max slack); then reads/MFMA interleaved so
// MFMA pipe fills while later B-pairs stream from LDS.
__device__ __forceinline__ void gemm4w(const char* gA, int ldaB,
                                       const char* gB, int ldbB,
                                       int nK, char* lds, f32x4 acc[8][8]) {
  const int tid = threadIdx.x;
  const int lane = tid & 63, wave = tid >> 6;   // 0..3
  const int wm = wave >> 1, wn = wave & 1;
  const int quad = lane >> 4, l16 = lane & 15;
  const int l7 = l16 & 7;
  const char* gA1 = gA + (long)128 * ldaB;
  const char* gB1 = gB + (long)128 * ldbB;
  f16x8 af[8][2], bf[8][2];
  // prologue: stage tile 0 (A0,A1,B0,B1 -> 16 loads)
  stage_half4(gA,  ldaB, 0, lds,         tid);
  stage_half4(gA1, ldaB, 0, lds + 16384, tid);
  stage_half4(gB,  ldbB, 0, lds + 32768, tid);
  stage_half4(gB1, ldbB, 0, lds + 49152, tid);
  for (int t = 0; t < nK; ++t) {
    char* buf  = lds + (t & 1) * 65536;
    char* nbuf = lds + ((t + 1) & 1) * 65536;
    const char* Ah = buf + wm * 16384;
    const char* Bh = buf + 32768 + wn * 16384;
    const bool st = (t + 1 < nK);
    const int kB = (t + 1) << 7;
    asm volatile("s_waitcnt vmcnt(0)" ::: "memory");  // t landed (issued 1 tile ago)
    __builtin_amdgcn_s_barrier(); FENCE;
    if (st) {                                          // stage t+1 with max slack
      stage_half4(gA,  ldaB, kB, nbuf,         tid);
      stage_half4(gA1, ldaB, kB, nbuf + 16384, tid);
      stage_half4(gB,  ldbB, kB, nbuf + 32768, tid);
      stage_half4(gB1, ldbB, kB, nbuf + 49152, tid);
    }
    RD_A8W(af, Ah);
    RD_B2W(bf, Bh, 0);
    RD_B2W(bf, Bh, 1);
    MFMA_P4(af, bf, acc, 0);
    RD_B2W(bf, Bh, 2);
    MFMA_P4(af, bf, acc, 1);
    RD_B2W(bf, Bh, 3);
    MFMA_P4(af, bf, acc, 2);
    MFMA_P4(af, bf, acc, 3);
  }
  __builtin_amdgcn_s_barrier(); FENCE;   // all waves' frag reads done -> LDS reusable
}

// ---------------------------------------------------------------- 128x256 DEEP-phase NT GEMM
// MEASURED R5/R8 (k_out) — FROZEN. 8 waves, wave 64x64; reads-one-phase-ahead.
#define D128_TILE(AC, B0C, AN, B0N, q) {                                         \
  char* Sc = lds + (q) * 49152;                                                  \
  char* Sn = lds + ((q) ^ 1) * 49152;                                            \
  const int kB = (t + 1) << 7;                                                   \
  stage_half(gA, ldaB, kB, Sn, tid);                                             \
  stage_half(gB, ldbB, kB, Sn + 16384, tid);                                     \
  asm volatile("s_waitcnt vmcnt(4)" ::: "memory");                               \
  __builtin_amdgcn_s_barrier(); FENCE;                                           \
  RD_B(b1, Sc + 32768);                                                          \
  MFMA8(AC, B0C, 0);                                                             \
  stage_half(gB1, ldbB, kB, Sn + 32768, tid);                                    \
  asm volatile("s_waitcnt vmcnt(2)" ::: "memory");                               \
  __builtin_amdgcn_s_barrier(); FENCE;                                           \
  RD_A(AN, Sn); RD_B(B0N, Sn + 16384);                                           \
  MFMA8(AC, b1, 1);                                                              \
}
#define D128_TAIL(AC, B0C, q) {                                                  \
  char* Sc = lds + (q) * 49152;                                                  \
  asm volatile("s_waitcnt vmcnt(0)" ::: "memory");                               \
  __builtin_amdgcn_s_barrier(); FENCE;                                           \
  RD_B(b1, Sc + 32768);                                                          \
  MFMA8(AC, B0C, 0);                                                             \
  MFMA8(AC, b1, 1);                                                              \
}

__device__ __forceinline__ void gemm_d128(const char* gA, int ldaB,
                                          const char* gB, int ldbB,
                                          int nK, char* lds, f32x4 acc[4][2][2]) {
  const int tid = threadIdx.x;
  const int lane = tid & 63, wave = tid >> 6;
  const int wm = wave >> 2, wn = wave & 3;
  const int quad = lane >> 4, l16 = lane & 15;
  const int l7 = l16 & 7;
  const char* gB1 = gB + (long)128 * ldbB;
  f16x8 aX[4][2], aY[4][2], b0X[2][2], b0Y[2][2], b1[2][2];
  stage_half(gA,  ldaB, 0, lds, tid);
  stage_half(gB,  ldbB, 0, lds + 16384, tid);
  stage_half(gB1, ldbB, 0, lds + 32768, tid);
  asm volatile("s_waitcnt vmcnt(2)" ::: "memory");   // A,B0 landed; B1 in flight
  __builtin_amdgcn_s_barrier(); FENCE;
  RD_A(aX, lds); RD_B(b0X, lds + 16384);
  for (int tb = 0; tb < nK - 2; tb += 2) {
    { const int t = tb;     D128_TILE(aX, b0X, aY, b0Y, 0) }
    { const int t = tb + 1; D128_TILE(aY, b0Y, aX, b0X, 1) }
  }
  { const int t = nK - 2;   D128_TILE(aX, b0X, aY, b0Y, 0) }
  D128_TAIL(aY, b0Y, 1)
  __builtin_amdgcn_s_barrier(); FENCE;   // all waves' frag reads done -> LDS reusable
}

// ---------------------------------------------------------------- fused QKV projection (+V transpose)
// NEW: 4-wave 256x256 tiles -> 384 blocks (XCD row-bands for X L2 reuse).
__global__ __launch_bounds__(256, 1) void k_qkv(const f16* __restrict__ X,
                                                const f16* __restrict__ Wq,
                                                const f16* __restrict__ Wk,
                                                const f16* __restrict__ Wv,
                                                const float* __restrict__ bq,
                                                const float* __restrict__ bk,
                                                const float* __restrict__ bv,
                                                f16* __restrict__ Q, f16* __restrict__ Ko,
                                                f16* __restrict__ Vt) {
  __shared__ __align__(16) char lds[131072];
  int fid = blockIdx.x;
  int xcd = fid & 7, k = fid >> 3;          // k in [0,48)
  int rowt = xcd * 4 + (k & 3);             // 0..31
  int colt = k >> 2;                        // 0..11
  int tm = rowt * 256;
  int w = colt >> 2;                        // 0:Q 1:K 2:V
  int tn = (colt & 3) * 256;
  const f16* Wsel = (w == 0) ? Wq : (w == 1) ? Wk : Wv;
  f32x4 acc[8][8];
#pragma unroll
  for (int i = 0; i < 8; ++i)
#pragma unroll
    for (int j = 0; j < 8; ++j) acc[i][j] = (f32x4){0.f, 0.f, 0.f, 0.f};
  gemm4w((const char*)(X + (long)tm * D_), D_ * 2,
         (const char*)(Wsel + (long)tn * D_), D_ * 2, D_ / 64, lds, acc);
  const int tid = threadIdx.x;
  const int lane = tid & 63, wave = tid >> 6;
  const int wm = wave >> 1, wn = wave & 1;
  const int quad = lane >> 4, l16 = lane & 15;
  if (w < 2) {
    const float* bias = w ? bk : bq;
    f16* outp = w ? Ko : Q;
#pragma unroll
    for (int j = 0; j < 8; ++j) {
      int col = tn + wn * 128 + j * 16 + l16;
      float bb = bias[col];
#pragma unroll
      for (int i = 0; i < 8; ++i) {
        int rbase = tm + wm * 128 + i * 16 + quad * 4;
#pragma unroll
        for (int r = 0; r < 4; ++r)
          outp[(long)(rbase + r) * D_ + col] = (_Float16)(acc[i][j][r] + bb);
      }
    }
  } else {
    // V: transpose through LDS in 2 feature-passes of 128 (pass == wn)
    int bidx = tm >> 11, ntok = tm & 2047;
    f16* VtB = Vt + (long)bidx * D_ * N_ + ntok;
    f16* ldsT = (f16*)lds;                  // 128 x 264 f16 = 67.6 KB
#pragma unroll
    for (int pass = 0; pass < 2; ++pass) {
      FENCE;
      __builtin_amdgcn_s_barrier();
      FENCE;
      if (wn == pass) {
#pragma unroll
        for (int j = 0; j < 8; ++j) {
          int fl = j * 16 + l16;                         // local feature 0..127
          float bb = bv[tn + pass * 128 + fl];
#pragma unroll
          for (int i = 0; i < 8; ++i) {
            int rl = wm * 128 + i * 16 + quad * 4;       // local token 0..255
            f16x4 p = { (_Float16)(acc[i][j][0] + bb), (_Float16)(acc[i][j][1] + bb),
                        (_Float16)(acc[i][j][2] + bb), (_Float16)(acc[i][j][3] + bb) };
            *(f16x4*)(ldsT + fl * 264 + rl) = p;
          }
        }
      }
      FENCE;
      __builtin_amdgcn_s_barrier();
      FENCE;
#pragma unroll
      for (int p = 0; p < 16; ++p) {
        int f = p * 8 + (tid >> 5);             // 0..127
        int cc = tid & 31;                      // 32 x 8 f16 = 256 tokens
        f16x8 v = *(const f16x8*)(ldsT + f * 264 + cc * 8);
        *(f16x8*)(VtB + (long)(tn + pass * 128 + f) * N_ + cc * 8) = v;
      }
    }
  }
}

// ---------------------------------------------------------------- scores: P' = exp(QK^T*delta)
// NEW: 4-wave 256x256 tile, 256 blocks (1/CU). 2-pass LDS bounce for coalesced stores.
__global__ __launch_bounds__(256, 1) void k_scores(const f16* __restrict__ Qf,
                                                   const f16* __restrict__ Kf,
                                                   f16* __restrict__ S,
                                                   float* __restrict__ rowsum) {
  __shared__ __align__(16) char lds[131072];
  int fid = blockIdx.x;
  int xcd = fid & 7, k = fid >> 3;
  int lin = xcd * 32 + k;
  int b = lin >> 6;
  int t = lin & 63;
  int rowt = t & 7, colt = t >> 3;
  int tm = rowt * 256, tn = colt * 256;
  f32x4 acc[8][8];
#pragma unroll
  for (int i = 0; i < 8; ++i)
#pragma unroll
    for (int j = 0; j < 8; ++j) acc[i][j] = (f32x4){0.f, 0.f, 0.f, 0.f};
  gemm4w((const char*)(Qf + (long)b * N_ * D_ + (long)tm * D_), D_ * 2,
         (const char*)(Kf + (long)b * N_ * D_ + (long)tn * D_), D_ * 2,
         D_ / 64, lds, acc);
  const int tid = threadIdx.x;
  const int lane = tid & 63, wave = tid >> 6;
  const int wm = wave >> 1, wn = wave & 1;
  const int quad = lane >> 4, l16 = lane & 15;
  f16* Sb = S + (long)b * N_ * N_;
  const float delta = 0.03125f;               // 1/sqrt(1024); exp <= ~e^6, f16-safe
  f16* ldsS = (f16*)lds;                      // 256 x 136 f16 per pass = 69.6 KB
  float rsum[8][4];
#pragma unroll
  for (int i = 0; i < 8; ++i)
#pragma unroll
    for (int r = 0; r < 4; ++r) rsum[i][r] = 0.f;
#pragma unroll
  for (int pass = 0; pass < 2; ++pass) {      // col-half == wn
    FENCE;
    __builtin_amdgcn_s_barrier();
    FENCE;
    if (wn == pass) {
#pragma unroll
      for (int i = 0; i < 8; ++i) {
        int rloc = wm * 128 + i * 16 + quad * 4;
#pragma unroll
        for (int j = 0; j < 8; ++j) {
          int col = j * 16 + l16;
#pragma unroll
          for (int r = 0; r < 4; ++r) {
            float e = __expf(acc[i][j][r] * delta);
            rsum[i][r] += e;
            ldsS[(rloc + r) * 136 + col] = (_Float16)e;
          }
        }
      }
    }
    FENCE;
    __builtin_amdgcn_s_barrier();
    FENCE;
#pragma unroll
    for (int p = 0; p < 16; ++p) {
      int row = p * 16 + (tid >> 4);
      int cc = tid & 15;
      f16x8 v = *(const f16x8*)(ldsS + row * 136 + cc * 8);
      *(f16x8*)(Sb + (long)(tm + row) * N_ + tn + pass * 128 + cc * 8) = v;
    }
  }
#pragma unroll
  for (int m = 1; m < 16; m <<= 1)
#pragma unroll
    for (int i = 0; i < 8; ++i)
#pragma unroll
      for (int r = 0; r < 4; ++r) rsum[i][r] += __shfl_xor(rsum[i][r], m);
  if (l16 == 0) {
    float* rs = rowsum + (long)b * N_ + tm;
#pragma unroll
    for (int i = 0; i < 8; ++i)
#pragma unroll
      for (int r = 0; r < 4; ++r)
        atomicAdd(rs + wm * 128 + i * 16 + quad * 4 + r, rsum[i][r]);
  }
}

// ---------------------------------------------------------------- O = (P' V)/rowsum * gamma + x
// FROZEN R5/R8 config: 128x256 tiles -> 256 blocks (1/CU), gemm_d128.
__global__ __launch_bounds__(512, 2) void k_out(const f16* __restrict__ P,
                                                const f16* __restrict__ Vt,
                                                const f16* __restrict__ xf,
                                                const float* __restrict__ gamma,
                                                const float* __restrict__ rowsum,
                                                float* __restrict__ out) {
  __shared__ __align__(16) char lds[98304];
  int fid = blockIdx.x;
  int xcd = fid & 7, kq = fid >> 3;
  int lin = xcd * 32 + kq;                  // 0..255
  int b = lin >> 6;                         // 0..3
  int t = lin & 63;
  int rowt = t >> 2, colt = t & 3;          // colt fast: P row-panel shared by 4 blocks
  int tm = rowt * 128, tn = colt * 256;
  f32x4 acc[4][2][2];
#pragma unroll
  for (int i = 0; i < 4; ++i)
#pragma unroll
    for (int Bh = 0; Bh < 2; ++Bh)
#pragma unroll
      for (int jn = 0; jn < 2; ++jn) acc[i][Bh][jn] = (f32x4){0.f, 0.f, 0.f, 0.f};
  gemm_d128((const char*)(P + (long)b * N_ * N_ + (long)tm * N_), N_ * 2,
            (const char*)(Vt + (long)b * D_ * N_ + (long)tn * N_), N_ * 2,
            N_ / 64, lds, acc);
  const int tid = threadIdx.x;
  const int lane = tid & 63, wave = tid >> 6;
  const int wm = wave >> 2, wn = wave & 3;
  const int quad = lane >> 4, l16 = lane & 15;
  float g = gamma[0];
  float inv[4][4];
#pragma unroll
  for (int i = 0; i < 4; ++i)
#pragma unroll
    for (int r = 0; r < 4; ++r)
      inv[i][r] = g / rowsum[(long)b * N_ + tm + wm * 64 + i * 16 + quad * 4 + r];
#pragma unroll
  for (int Bh = 0; Bh < 2; ++Bh)
#pragma unroll
    for (int jn = 0; jn < 2; ++jn) {
      int col = tn + Bh * 128 + wn * 32 + jn * 16 + l16;
#pragma unroll
      for (int i = 0; i < 4; ++i) {
        int rbase = tm + wm * 64 + i * 16 + quad * 4;
#pragma unroll
        for (int r = 0; r < 4; ++r) {
          long idx = (long)b * N_ * D_ + (long)(rbase + r) * D_ + col;
          out[idx] = acc[i][Bh][jn][r] * inv[i][r] + (float)xf[idx];
        }
      }
    }
}

// ---------------------------------------------------------------- launch
extern "C" void kernel_launch(void* const* d_in, const int* in_sizes, int n_in,
                              void* d_out, int out_size, void* d_ws, size_t ws_size,
                              hipStream_t stream) {
  const float* x  = (const float*)d_in[0];
  const float* Wq = (const float*)d_in[1];
  const float* bq = (const float*)d_in[2];
  const float* Wk = (const float*)d_in[3];
  const float* bk = (const float*)d_in[4];
  const float* Wv = (const float*)d_in[5];
  const float* bv = (const float*)d_in[6];
  const float* gamma = (const float*)d_in[7];
  float* out = (float*)d_out;
  char* ws = (char*)d_ws;

  // ws layout: Xb stays ALIVE through k_out (x re-read as f16).
  // S overlays only the dead W buffers. Peak 96 MB (+32 KB rowsum).
  f16* Qb  = (f16*)(ws);                      // 0..16 MB
  f16* Kb  = (f16*)(ws + (16u << 20));        // 16..32 MB
  f16* Vt  = (f16*)(ws + (32u << 20));        // 32..48 MB (written directly by k_qkv)
  f16* Xb  = (f16*)(ws + (48u << 20));        // 48..64 MB (alive through k_out)
  f16* Wqb = (f16*)(ws + (64u << 20));        // 64..66 MB (dead after k_qkv)
  f16* Wkb = (f16*)(ws + (66u << 20));        // 66..68 MB
  f16* Wvb = (f16*)(ws + (68u << 20));        // 68..70 MB
  f16* S   = (f16*)(ws + (64u << 20));        // 64..96 MB, overlays dead W's
  float* rowsum = (float*)(ws + (96u << 20)); // 32 KB

  k_cast_all<<<11296, 256, 0, stream>>>((const float4*)x, (const float4*)Wq,
                                        (const float4*)Wk, (const float4*)Wv,
                                        (f16x4*)Xb, (f16x4*)Wqb, (f16x4*)Wkb, (f16x4*)Wvb,
                                        rowsum);
  k_qkv<<<384, 256, 0, stream>>>(Xb, Wqb, Wkb, Wvb, bq, bk, bv, Qb, Kb, Vt);
  k_scores<<<256, 256, 0, stream>>>(Qb, Kb, S, rowsum);
  k_out<<<256, 512, 0, stream>>>(S, Vt, Xb, gamma, rowsum, out);
}